// Round 3
// baseline (76.262 us; speedup 1.0000x reference)
//
#include <hip/hip_runtime.h>

// BoundaryLoss: mean(sigmoid(logits) * EDT2D(target)), B=8, H=W=256.
//
// Pass 1 (row): exact 1D row distance via wave shuffle-scans (O(W) per row,
//               integer-exact), dr2 = d^2 to workspace. Also zeroes d_out.
// Pass 2 (col): exact column EDT, strength-reduced
//                 min_j (i-j)^2 + dr2_j = i^2 + min_j (j^2 + dr2_j - 2ij)
//               with the candidate j-range split across 2 waves per column
//               (4 waves/SIMD occupancy), fused sqrt+sigmoid+reduce and a
//               single atomicAdd per block into d_out.
// All candidate values are exact integers < 2^24 in fp32 -> matches reference
// bit-exactly for rows containing foreground (always, with this RNG).

#define BIGF 1000000.0f
#define BIG2 (BIGF * BIGF)
#define BIGI (1 << 20)

constexpr int B = 8;
constexpr int H = 256;
constexpr int W = 256;
constexpr int NPIX = B * H * W;   // 524288

__device__ __forceinline__ float block_reduce_sum_256(float v) {
    #pragma unroll
    for (int off = 32; off > 0; off >>= 1)
        v += __shfl_down(v, off, 64);
    __shared__ float s[4];
    const int lane = threadIdx.x & 63;
    const int wid  = threadIdx.x >> 6;
    if (lane == 0) s[wid] = v;
    __syncthreads();
    if (wid == 0) {
        v = (lane < 4) ? s[lane] : 0.0f;
        v += __shfl_down(v, 2, 64);
        v += __shfl_down(v, 1, 64);
    }
    return v;  // valid on thread 0
}

// Pass 1: scan-based exact row distances. 512 blocks x 256 thr, 1 wave/row.
__global__ __launch_bounds__(256) void row_dist_kernel(
        const int* __restrict__ target, float* __restrict__ dr2,
        float* __restrict__ out) {
    if (blockIdx.x == 0 && threadIdx.x == 0) out[0] = 0.0f;  // for pass-2 atomics

    const int lane = threadIdx.x & 63;
    const int wv   = threadIdx.x >> 6;
    const int row  = (blockIdx.x << 2) + wv;
    const int p0   = lane << 2;

    const int4 tv = *(const int4*)(target + row * W + p0);

    // ---- last foreground index <= p (prefix max of fg?idx:-1) ----
    const int l0 = (tv.x > 0) ? p0     : -1;
    const int l1 = (tv.y > 0) ? p0 + 1 : l0;
    const int l2 = (tv.z > 0) ? p0 + 2 : l1;
    const int l3 = (tv.w > 0) ? p0 + 3 : l2;
    int v = l3;                              // per-lane segment max
    #pragma unroll
    for (int off = 1; off < 64; off <<= 1) {
        const int u = __shfl_up(v, off, 64);
        if (lane >= off) v = max(v, u);
    }
    int exv = __shfl_up(v, 1, 64);           // exclusive: lanes < lane
    if (lane == 0) exv = -1;
    const int last0 = max(exv, l0), last1 = max(exv, l1);
    const int last2 = max(exv, l2), last3 = max(exv, l3);

    // ---- next foreground index >= p (suffix min of fg?idx:INF) ----
    const int r3 = (tv.w > 0) ? p0 + 3 : BIGI;
    const int r2 = (tv.z > 0) ? p0 + 2 : r3;
    const int r1 = (tv.y > 0) ? p0 + 1 : r2;
    const int r0 = (tv.x > 0) ? p0     : r1;
    int s = r0;                              // per-lane segment min
    #pragma unroll
    for (int off = 1; off < 64; off <<= 1) {
        const int u = __shfl_down(s, off, 64);
        if (lane < 64 - off) s = min(s, u);
    }
    int exs = __shfl_down(s, 1, 64);         // exclusive: lanes > lane
    if (lane == 63) exs = BIGI;
    const int nxt0 = min(exs, r0), nxt1 = min(exs, r1);
    const int nxt2 = min(exs, r2), nxt3 = min(exs, r3);

    const int dl0 = (last0 >= 0) ? p0     - last0 : BIGI;
    const int dl1 = (last1 >= 0) ? p0 + 1 - last1 : BIGI;
    const int dl2 = (last2 >= 0) ? p0 + 2 - last2 : BIGI;
    const int dl3 = (last3 >= 0) ? p0 + 3 - last3 : BIGI;
    const int d0 = min(dl0, nxt0 - p0);
    const int d1 = min(dl1, nxt1 - (p0 + 1));
    const int d2 = min(dl2, nxt2 - (p0 + 2));
    const int d3 = min(dl3, nxt3 - (p0 + 3));

    float4 o;
    o.x = (d0 < W) ? (float)(d0 * d0) : BIG2;
    o.y = (d1 < W) ? (float)(d1 * d1) : BIG2;
    o.z = (d2 < W) ? (float)(d2 * d2) : BIG2;
    o.w = (d3 < W) ? (float)(d3 * d3) : BIG2;
    *(float4*)(dr2 + row * W + p0) = o;
}

// 16 candidates (4 outputs x 4 j's) per LDS float4.
__device__ __forceinline__ void upd16(const float4 m, float j0,
                                      float n0, float n1, float n2, float n3,
                                      float& b0, float& b1, float& b2, float& b3) {
    const float j1 = j0 + 1.0f, j2 = j0 + 2.0f, j3 = j0 + 3.0f;
    {
        const float c0 = fmaf(n0, j0, m.x), c1 = fmaf(n0, j1, m.y);
        const float c2 = fmaf(n0, j2, m.z), c3 = fmaf(n0, j3, m.w);
        b0 = fminf(b0, fminf(fminf(c0, c1), fminf(c2, c3)));
    }
    {
        const float c0 = fmaf(n1, j0, m.x), c1 = fmaf(n1, j1, m.y);
        const float c2 = fmaf(n1, j2, m.z), c3 = fmaf(n1, j3, m.w);
        b1 = fminf(b1, fminf(fminf(c0, c1), fminf(c2, c3)));
    }
    {
        const float c0 = fmaf(n2, j0, m.x), c1 = fmaf(n2, j1, m.y);
        const float c2 = fmaf(n2, j2, m.z), c3 = fmaf(n2, j3, m.w);
        b2 = fminf(b2, fminf(fminf(c0, c1), fminf(c2, c3)));
    }
    {
        const float c0 = fmaf(n3, j0, m.x), c1 = fmaf(n3, j1, m.y);
        const float c2 = fmaf(n3, j2, m.z), c3 = fmaf(n3, j3, m.w);
        b3 = fminf(b3, fminf(fminf(c0, c1), fminf(c2, c3)));
    }
}

// Pass 2: 1024 blocks x 256 thr. Block -> (image b, 2 columns). Wave wv:
// column c = wv>>1, candidate half = wv&1 (j in [128*half, 128*half+128)).
__global__ __launch_bounds__(256) void col_pass_kernel(
        const float* __restrict__ logits, const float* __restrict__ dr2,
        float* __restrict__ out) {
    __shared__ float s_q[2][256];
    __shared__ float s_part[4][256];

    const int t  = threadIdx.x;
    const int b  = blockIdx.x >> 7;          // 128 blocks per image
    const int w0 = (blockIdx.x & 127) << 1;

    // stage q_j = j^2 + dr2[j][w0+c]  (thread t -> j = t; 8B coalesced load)
    const float2 v  = *(const float2*)(dr2 + (b * H + t) * W + w0);
    const float ft  = (float)t;
    const float fj2 = ft * ft;               // exact (< 2^24)
    s_q[0][t] = fj2 + v.x;
    s_q[1][t] = fj2 + v.y;
    __syncthreads();

    const int lane  = t & 63;
    const int wv    = t >> 6;
    const int c     = wv >> 1;
    const int jbase = (wv & 1) << 7;         // 0 or 128

    const float i0f = (float)lane,         i1f = (float)(lane + 64);
    const float i2f = (float)(lane + 128), i3f = (float)(lane + 192);
    const float n0 = -2.0f * i0f, n1 = -2.0f * i1f;
    const float n2 = -2.0f * i2f, n3 = -2.0f * i3f;
    float b0 = 4e12f, b1 = 4e12f, b2 = 4e12f, b3 = 4e12f;

    float fj = (float)jbase;
    #pragma unroll 4
    for (int jv = 0; jv < 32; ++jv, fj += 4.0f) {
        const float4 m = *(const float4*)&s_q[c][jbase + (jv << 2)];
        upd16(m, fj, n0, n1, n2, n3, b0, b1, b2, b3);
    }

    s_part[wv][lane]       = b0;
    s_part[wv][lane + 64]  = b1;
    s_part[wv][lane + 128] = b2;
    s_part[wv][lane + 192] = b3;
    __syncthreads();

    // epilogue: thread t -> output row i = t, both columns
    const float2 lg = *(const float2*)(logits + (b * H + t) * W + w0);
    float acc;
    {
        const float best = fminf(s_part[0][t], s_part[1][t]);
        const float dist = sqrtf(fmaf(ft, ft, best));
        acc = dist / (1.0f + expf(-lg.x));
    }
    {
        const float best = fminf(s_part[2][t], s_part[3][t]);
        const float dist = sqrtf(fmaf(ft, ft, best));
        acc += dist / (1.0f + expf(-lg.y));
    }

    const float sum = block_reduce_sum_256(acc);
    if (t == 0) atomicAdd(out, sum * (1.0f / (float)NPIX));
}

extern "C" void kernel_launch(void* const* d_in, const int* in_sizes, int n_in,
                              void* d_out, int out_size, void* d_ws, size_t ws_size,
                              hipStream_t stream) {
    const float* logits = (const float*)d_in[0];
    const int*   target = (const int*)d_in[1];
    float*       out    = (float*)d_out;
    float*       dr2    = (float*)d_ws;      // NPIX floats (2 MB)

    row_dist_kernel<<<B * H / 4, 256, 0, stream>>>(target, dr2, out);
    col_pass_kernel<<<B * W / 2, 256, 0, stream>>>(logits, dr2, out);
}